// Round 1
// baseline (200.094 us; speedup 1.0000x reference)
//
#include <hip/hip_runtime.h>

#define RREG 36
#define TTOK 64
#define DDIM 1024
#define TH   32   // tokens per block (T-split: 2 blocks per batch)

typedef __attribute__((ext_vector_type(4))) float f32x4;
typedef __attribute__((ext_vector_type(8))) short bf16x8;

__device__ __forceinline__ unsigned short f2bf(float x) {
  unsigned int u = __float_as_uint(x);
  u += 0x7fffu + ((u >> 16) & 1u);   // round-to-nearest-even
  return (unsigned short)(u >> 16);
}

// Barrier that waits only on LDS ops (lgkmcnt), NOT vmcnt: keeps prefetch
// global loads in flight across the barrier (avoids __syncthreads' full
// vmcnt(0) drain). All staging here is reg->ds_write, so lgkmcnt(0) is
// sufficient for cross-thread LDS visibility.
__device__ __forceinline__ void lds_barrier() {
  asm volatile("s_waitcnt lgkmcnt(0)" ::: "memory");
  __builtin_amdgcn_s_barrier();
}

// LDS layout (bytes), per block (31,680 total -> 2 blocks/CU fits easily):
//   [0, 8704)       scap  [32][136] bf16   (phase A)        -- aliased by:
//   [0, 14336)      simgT [128][56] bf16   (phase B)
//   [8704, 21760)   simg  [48][136] bf16   (phase A)
//   [21760, 28288)  ssc   [48][34]  f32    (raw dots, local t)
//   [28288, 31360)  satt  [32][48]  bf16   (attn^T, cols>=36 zero)
//   [31360, 31552)  sni   [48] f32  img norms
//   [31552, 31680)  snc   [32] f32  cap norms (local tokens)
__global__ __launch_bounds__(512, 4) void scan_fused(
    const float* __restrict__ img, const float* __restrict__ cap,
    float* __restrict__ out) {
  __shared__ __align__(16) unsigned char smem[31680];

  unsigned short* scap  = (unsigned short*)(smem + 0);
  unsigned short* simg  = (unsigned short*)(smem + 8704);
  unsigned short* simgT = (unsigned short*)(smem + 0);
  float* ssc            = (float*)(smem + 21760);
  unsigned short* satt  = (unsigned short*)(smem + 28288);
  float* sni            = (float*)(smem + 31360);
  float* snc            = (float*)(smem + 31552);

  const int tid  = threadIdx.x;
  const int lane = tid & 63;
  const int wave = tid >> 6;        // 0..7
  const int fm   = lane & 15;
  const int kq   = lane >> 4;

  // XCD-pairing swizzle: dispatch round-robins blockIdx%8 across XCDs.
  // Map so blocks i and i+8 (same XCD) are the two halves of one batch ->
  // shared img tile is an L2 hit for the sibling and for phase B.
  const int i     = blockIdx.x;
  const int b     = ((i & 7) << 5) + (i >> 4);   // 0..255, bijective
  const int tbase = ((i >> 3) & 1) * TH;         // 0 or 32

  const float* imgb = img + (size_t)b * RREG * DDIM;
  const float* capb = cap + ((size_t)b * TTOK + tbase) * DDIM;
  float*       outb = out + ((size_t)b * TTOK + tbase) * DDIM;

  const int trow = tid >> 5;        // 0..15 (row owner for staging + norms)
  const int d4   = tid & 31;        // float4 slot within 128-d chunk

  const int mt = wave >> 1;         // phase A tiles (waves 0..5): mt 0..2
  const int nt = wave & 1;          //                             nt 0..1

  f32x4 acc = {0.f, 0.f, 0.f, 0.f};
  float cn0 = 0.f, cn1 = 0.f, in0 = 0.f, in1 = 0.f, in2 = 0.f;

  // ---------------- Phase A: dots = img(36x1024) . cap_half^T(1024x32) ----------------
  // Register prefetch: chunk c+1's loads issued before staging chunk c.
  float4 pc0, pc1, pi0, pi1, pi2;
  {
    const float* cp = capb + d4 * 4;
    const float* ip = imgb + d4 * 4;
    pc0 = *(const float4*)(cp + trow * DDIM);
    pc1 = *(const float4*)(cp + (trow + 16) * DDIM);
    pi0 = *(const float4*)(ip + trow * DDIM);
    pi1 = *(const float4*)(ip + (trow + 16) * DDIM);
    pi2 = make_float4(0.f, 0.f, 0.f, 0.f);
    if (trow < RREG - 32) pi2 = *(const float4*)(ip + (trow + 32) * DDIM);
  }

#pragma unroll
  for (int c = 0; c < 8; ++c) {
    float4 nc0, nc1, ni0, ni1, ni2;
    if (c < 7) {   // issue next chunk's loads early (stay in flight across barriers)
      const float* cp = capb + (c + 1) * 128 + d4 * 4;
      const float* ip = imgb + (c + 1) * 128 + d4 * 4;
      nc0 = *(const float4*)(cp + trow * DDIM);
      nc1 = *(const float4*)(cp + (trow + 16) * DDIM);
      ni0 = *(const float4*)(ip + trow * DDIM);
      ni1 = *(const float4*)(ip + (trow + 16) * DDIM);
      ni2 = make_float4(0.f, 0.f, 0.f, 0.f);
      if (trow < RREG - 32) ni2 = *(const float4*)(ip + (trow + 32) * DDIM);
    }
    // stage current chunk (bf16) + fp32 norm^2 partials
    {
      cn0 += pc0.x * pc0.x + pc0.y * pc0.y + pc0.z * pc0.z + pc0.w * pc0.w;
      ushort4 p; p.x = f2bf(pc0.x); p.y = f2bf(pc0.y); p.z = f2bf(pc0.z); p.w = f2bf(pc0.w);
      *(ushort4*)(scap + trow * 136 + d4 * 4) = p;

      cn1 += pc1.x * pc1.x + pc1.y * pc1.y + pc1.z * pc1.z + pc1.w * pc1.w;
      ushort4 q; q.x = f2bf(pc1.x); q.y = f2bf(pc1.y); q.z = f2bf(pc1.z); q.w = f2bf(pc1.w);
      *(ushort4*)(scap + (trow + 16) * 136 + d4 * 4) = q;

      in0 += pi0.x * pi0.x + pi0.y * pi0.y + pi0.z * pi0.z + pi0.w * pi0.w;
      ushort4 r0; r0.x = f2bf(pi0.x); r0.y = f2bf(pi0.y); r0.z = f2bf(pi0.z); r0.w = f2bf(pi0.w);
      *(ushort4*)(simg + trow * 136 + d4 * 4) = r0;

      in1 += pi1.x * pi1.x + pi1.y * pi1.y + pi1.z * pi1.z + pi1.w * pi1.w;
      ushort4 r1; r1.x = f2bf(pi1.x); r1.y = f2bf(pi1.y); r1.z = f2bf(pi1.z); r1.w = f2bf(pi1.w);
      *(ushort4*)(simg + (trow + 16) * 136 + d4 * 4) = r1;

      in2 += pi2.x * pi2.x + pi2.y * pi2.y + pi2.z * pi2.z + pi2.w * pi2.w;
      ushort4 r2; r2.x = f2bf(pi2.x); r2.y = f2bf(pi2.y); r2.z = f2bf(pi2.z); r2.w = f2bf(pi2.w);
      *(ushort4*)(simg + (trow + 32) * 136 + d4 * 4) = r2;   // zeros for rows >= 36
    }
    lds_barrier();
    if (wave < 6) {
      const unsigned short* arow = simg + (mt * 16 + fm) * 136 + kq * 8;
      const unsigned short* brow = scap + (nt * 16 + fm) * 136 + kq * 8;
#pragma unroll
      for (int ks = 0; ks < 4; ++ks) {
        bf16x8 av = *(const bf16x8*)(arow + ks * 32);
        bf16x8 bv = *(const bf16x8*)(brow + ks * 32);
        acc = __builtin_amdgcn_mfma_f32_16x16x32_bf16(av, bv, acc, 0, 0, 0);
      }
    }
    lds_barrier();   // frag reads done before next chunk's LDS writes
    if (c < 7) { pc0 = nc0; pc1 = nc1; pi0 = ni0; pi1 = ni1; pi2 = ni2; }
  }

  // dump raw dots: D row=(kq*4+i), col=fm  ->  ssc[r][tloc]
  if (wave < 6) {
#pragma unroll
    for (int ii = 0; ii < 4; ++ii)
      ssc[(mt * 16 + kq * 4 + ii) * 34 + nt * 16 + fm] = acc[ii];
  }
  // norm reductions across 32-thread row groups
#pragma unroll
  for (int off = 16; off > 0; off >>= 1) {
    cn0 += __shfl_down(cn0, off, 32);
    cn1 += __shfl_down(cn1, off, 32);
    in0 += __shfl_down(in0, off, 32);
    in1 += __shfl_down(in1, off, 32);
    in2 += __shfl_down(in2, off, 32);
  }
  if ((tid & 31) == 0) {
    snc[trow]      = sqrtf(cn0);
    snc[trow + 16] = sqrtf(cn1);
    sni[trow]      = sqrtf(in0);
    sni[trow + 16] = sqrtf(in1);
    if (trow < RREG - 32) sni[trow + 32] = sqrtf(in2);
  }
  lds_barrier();

  // ---------------- softmax over r, per local t (wave 0; lane = tloc) ----------------
  if (wave == 0 && lane < TH) {
    float cn = snc[lane];
    float s[RREG];
    float mx = -1e30f;
#pragma unroll
    for (int r = 0; r < RREG; ++r) {
      float denom = fmaxf(sni[r] * cn, 1e-8f);
      float v = ssc[r * 34 + lane] / denom;
      s[r] = v;
      mx = fmaxf(mx, v);
    }
    float sum = 0.f;
#pragma unroll
    for (int r = 0; r < RREG; ++r) { float e = __expf(s[r] - mx); s[r] = e; sum += e; }
    float rinv = 1.f / sum;
    unsigned short* ap = satt + lane * 48;
#pragma unroll
    for (int r = 0; r < RREG; ++r) ap[r] = f2bf(s[r] * rinv);
#pragma unroll
    for (int r = RREG; r < 48; ++r) ap[r] = 0;
  }
  lds_barrier();

  // ---------------- Phase B: out_half = attn^T(32x36) . img(36x1024) ----------------
  const int mtB = wave >> 2;   // t-tile 0..1
  const unsigned short* arowB = satt + (mtB * 16 + fm) * 48;
  bf16x8 a1 = *(const bf16x8*)(arowB + kq * 8);            // k = 0..31
  bf16x8 a2 = {0, 0, 0, 0, 0, 0, 0, 0};                    // k = 32..47
  if (kq < 2) a2 = *(const bf16x8*)(arowB + 32 + kq * 8);

  // staging map: thread owns column group dloc (4 d's), rows rB0, rB0+16, rB0+32
  const int rB0  = tid & 15;
  const int dloc = (((tid >> 4) & 3) + 4 * (tid >> 6)) * 4;   // 0..124 step 4

  float4 q0, q1, q2;
  {
    const float* ip = imgb + dloc;
    q0 = *(const float4*)(ip + rB0 * DDIM);
    q1 = *(const float4*)(ip + (rB0 + 16) * DDIM);
    q2 = make_float4(0.f, 0.f, 0.f, 0.f);
    if (rB0 + 32 < RREG) q2 = *(const float4*)(ip + (rB0 + 32) * DDIM);
  }

#pragma unroll
  for (int cb = 0; cb < 8; ++cb) {
    float4 n0, n1, n2;
    if (cb < 7) {   // prefetch next img chunk
      const float* ip = imgb + (cb + 1) * 128 + dloc;
      n0 = *(const float4*)(ip + rB0 * DDIM);
      n1 = *(const float4*)(ip + (rB0 + 16) * DDIM);
      n2 = make_float4(0.f, 0.f, 0.f, 0.f);
      if (rB0 + 32 < RREG) n2 = *(const float4*)(ip + (rB0 + 32) * DDIM);
    }
    // stage img transposed: simgT[d][r], rows r>=36 zero (NaN-safe for a*0)
    {
      unsigned short* tp = simgT + dloc * 56;
      tp[0 * 56 + rB0] = f2bf(q0.x);
      tp[1 * 56 + rB0] = f2bf(q0.y);
      tp[2 * 56 + rB0] = f2bf(q0.z);
      tp[3 * 56 + rB0] = f2bf(q0.w);
      tp[0 * 56 + rB0 + 16] = f2bf(q1.x);
      tp[1 * 56 + rB0 + 16] = f2bf(q1.y);
      tp[2 * 56 + rB0 + 16] = f2bf(q1.z);
      tp[3 * 56 + rB0 + 16] = f2bf(q1.w);
      tp[0 * 56 + rB0 + 32] = f2bf(q2.x);
      tp[1 * 56 + rB0 + 32] = f2bf(q2.y);
      tp[2 * 56 + rB0 + 32] = f2bf(q2.z);
      tp[3 * 56 + rB0 + 32] = f2bf(q2.w);
    }
    lds_barrier();
#pragma unroll
    for (int j = 0; j < 2; ++j) {
      const int ntB = (wave & 3) * 2 + j;     // d-tile within chunk: 0..7
      const unsigned short* brow = simgT + (ntB * 16 + fm) * 56;
      bf16x8 b1 = *(const bf16x8*)(brow + kq * 8);
      bf16x8 b2 = {0, 0, 0, 0, 0, 0, 0, 0};
      if (kq < 2) b2 = *(const bf16x8*)(brow + 32 + kq * 8);
      f32x4 o = {0.f, 0.f, 0.f, 0.f};
      o = __builtin_amdgcn_mfma_f32_16x16x32_bf16(a1, b1, o, 0, 0, 0);
      o = __builtin_amdgcn_mfma_f32_16x16x32_bf16(a2, b2, o, 0, 0, 0);
#pragma unroll
      for (int ii = 0; ii < 4; ++ii)
        outb[(mtB * 16 + kq * 4 + ii) * DDIM + cb * 128 + ntB * 16 + fm] = o[ii];
    }
    if (cb < 7) {
      lds_barrier();   // frag reads done before next chunk's writes
      q0 = n0; q1 = n1; q2 = n2;
    }
  }
}

extern "C" void kernel_launch(void* const* d_in, const int* in_sizes, int n_in,
                              void* d_out, int out_size, void* d_ws, size_t ws_size,
                              hipStream_t stream) {
  const float* img = (const float*)d_in[0];   // (256, 36, 1024) fp32
  const float* cap = (const float*)d_in[1];   // (256, 64, 1024) fp32
  // d_in[2] = cap_mask, unused by reference forward
  float* out = (float*)d_out;                 // (256, 64, 1024) fp32
  scan_fused<<<dim3(512), dim3(512), 0, stream>>>(img, cap, out);
}

// Round 2
// 163.086 us; speedup vs baseline: 1.2269x; 1.2269x over previous
//
#include <hip/hip_runtime.h>

#define RREG 36
#define TTOK 64
#define DDIM 1024

typedef __attribute__((ext_vector_type(4))) float f32x4;
typedef __attribute__((ext_vector_type(8))) short bf16x8;

__device__ __forceinline__ unsigned short f2bf(float x) {
  unsigned int u = __float_as_uint(x);
  u += 0x7fffu + ((u >> 16) & 1u);   // round-to-nearest-even
  return (unsigned short)(u >> 16);
}

// Barrier that waits only on LDS ops (lgkmcnt), NOT vmcnt: prefetched global
// loads stay in flight across it. All LDS staging is reg->ds_write, so
// lgkmcnt(0) gives full cross-thread LDS visibility.
__device__ __forceinline__ void lds_barrier() {
  asm volatile("s_waitcnt lgkmcnt(0)" ::: "memory");
  __builtin_amdgcn_s_barrier();
}

// LDS layout (60,928 B total), heavily time-aliased:
//   [0,17408)      scap0 [64][136] bf16  (phase A buf0)   } aliased by
//   [17408,30464)  simg0 [48][136] bf16  (phase A buf0)   }  simgT0 [128][56] @0
//   [30464,47872)  scap1 (phase A buf1)                   }  simgT1 @14336
//   [47872,60928)  simg1 (phase A buf1)                   }
//   after phase A's last MFMA (reads buf1), buf1 region is reused:
//   [30464,43136)  ssc  [48][66] f32   (raw dots)
//   [43136,49280)  satt [64][48] bf16  (attn^T, cols>=36 zero)
//   [49280,49472)  sni  [48] f32 ; [49472,49728) snc [64] f32
__global__ __launch_bounds__(1024, 4) void scan_fused(
    const float* __restrict__ img, const float* __restrict__ cap,
    float* __restrict__ out) {
  __shared__ __align__(16) unsigned char smem[60928];

  float* ssc            = (float*)(smem + 30464);
  unsigned short* satt  = (unsigned short*)(smem + 43136);
  float* sni            = (float*)(smem + 49280);
  float* snc            = (float*)(smem + 49472);

  const int tid  = threadIdx.x;
  const int lane = tid & 63;
  const int wave = tid >> 6;        // 0..15
  const int fm   = lane & 15;
  const int kq   = lane >> 4;
  const int b    = blockIdx.x;

  const float* imgb = img + (size_t)b * RREG * DDIM;
  const float* capb = cap + (size_t)b * TTOK * DDIM;
  float*       outb = out + (size_t)b * TTOK * DDIM;

  const int trow = tid >> 5;        // 0..31 (staging row owner)
  const int d4   = tid & 31;        // float4 slot within 128-d chunk
  const int mt   = wave >> 2;       // phase A tiles (waves 0..11)
  const int nt   = wave & 3;

  // phase B staging map (rows rB / rB2, column group dlB), round-0 equivalent
  const int rB   = ((tid >> 9) << 4) | (tid & 15);               // 0..31
  const int gB   = tid & 511;
  const int dlB  = ((((gB >> 4) & 3) + ((gB >> 6) << 2)) << 2);  // 0..124 step 4
  const bool hasB2 = (tid < 512);
  const int rB2  = 32 + (tid & 15);                              // 32..47

  f32x4 acc = {0.f, 0.f, 0.f, 0.f};
  float cn0 = 0.f, cn1 = 0.f, in0 = 0.f, in1 = 0.f;

  auto issueA = [&](int c, float4& c0v, float4& c1v, float4& i0v, float4& i1v) {
    const float* cp = capb + c * 128 + d4 * 4;
    const float* ip = imgb + c * 128 + d4 * 4;
    c0v = *(const float4*)(cp + trow * DDIM);
    c1v = *(const float4*)(cp + (trow + 32) * DDIM);
    i0v = *(const float4*)(ip + trow * DDIM);
    i1v = make_float4(0.f, 0.f, 0.f, 0.f);
    if (tid < 512 && trow + 32 < RREG)
      i1v = *(const float4*)(ip + (trow + 32) * DDIM);
  };
  auto stageA = [&](int par, const float4& c0v, const float4& c1v,
                    const float4& i0v, const float4& i1v) {
    unsigned short* sc = (unsigned short*)(smem + par * 30464);
    unsigned short* si = sc + 8704;   // +17408 bytes
    cn0 += c0v.x * c0v.x + c0v.y * c0v.y + c0v.z * c0v.z + c0v.w * c0v.w;
    ushort4 p; p.x = f2bf(c0v.x); p.y = f2bf(c0v.y); p.z = f2bf(c0v.z); p.w = f2bf(c0v.w);
    *(ushort4*)(sc + trow * 136 + d4 * 4) = p;
    cn1 += c1v.x * c1v.x + c1v.y * c1v.y + c1v.z * c1v.z + c1v.w * c1v.w;
    ushort4 q; q.x = f2bf(c1v.x); q.y = f2bf(c1v.y); q.z = f2bf(c1v.z); q.w = f2bf(c1v.w);
    *(ushort4*)(sc + (trow + 32) * 136 + d4 * 4) = q;
    in0 += i0v.x * i0v.x + i0v.y * i0v.y + i0v.z * i0v.z + i0v.w * i0v.w;
    ushort4 r0; r0.x = f2bf(i0v.x); r0.y = f2bf(i0v.y); r0.z = f2bf(i0v.z); r0.w = f2bf(i0v.w);
    *(ushort4*)(si + trow * 136 + d4 * 4) = r0;
    if (tid < 512) {
      in1 += i1v.x * i1v.x + i1v.y * i1v.y + i1v.z * i1v.z + i1v.w * i1v.w;
      ushort4 r1; r1.x = f2bf(i1v.x); r1.y = f2bf(i1v.y); r1.z = f2bf(i1v.z); r1.w = f2bf(i1v.w);
      *(ushort4*)(si + (trow + 32) * 136 + d4 * 4) = r1;   // zeros for rows >= 36
    }
  };
  auto mfmaA = [&](int par) {
    if (wave < 12) {
      const unsigned short* sc = (const unsigned short*)(smem + par * 30464);
      const unsigned short* si = sc + 8704;
      const unsigned short* arow = si + (mt * 16 + fm) * 136 + kq * 8;
      const unsigned short* brow = sc + (nt * 16 + fm) * 136 + kq * 8;
#pragma unroll
      for (int ks = 0; ks < 4; ++ks) {
        bf16x8 av = *(const bf16x8*)(arow + ks * 32);
        bf16x8 bv = *(const bf16x8*)(brow + ks * 32);
        acc = __builtin_amdgcn_mfma_f32_16x16x32_bf16(av, bv, acc, 0, 0, 0);
      }
    }
  };
  auto issueB = [&](int cb, float4& q0, float4& q1) {
    const float* ip = imgb + cb * 128 + dlB;
    q0 = *(const float4*)(ip + rB * DDIM);
    q1 = make_float4(0.f, 0.f, 0.f, 0.f);
    if (hasB2 && rB2 < RREG) q1 = *(const float4*)(ip + rB2 * DDIM);
  };
  auto stageB = [&](int par, const float4& q0, const float4& q1) {
    unsigned short* tp = (unsigned short*)(smem + par * 14336) + dlB * 56;
    tp[0 * 56 + rB] = f2bf(q0.x);
    tp[1 * 56 + rB] = f2bf(q0.y);
    tp[2 * 56 + rB] = f2bf(q0.z);
    tp[3 * 56 + rB] = f2bf(q0.w);
    if (hasB2) {   // rows 32..47 (zeros for >= 36)
      tp[0 * 56 + rB2] = f2bf(q1.x);
      tp[1 * 56 + rB2] = f2bf(q1.y);
      tp[2 * 56 + rB2] = f2bf(q1.z);
      tp[3 * 56 + rB2] = f2bf(q1.w);
    }
  };

  // ---------------- Phase A: dots = img(36x1024) . cap^T(1024x64) ----------------
  float4 tc0, tc1, ti0, ti1;          // chunk 0 (staged pre-loop)
  float4 cc0, cc1, ci0, ci1;          // chunk c+1 (to stage at iter c)
  float4 nc0, nc1, ni0, ni1;          // chunk c+2 (issued at iter c)
  float4 bq0a, bq0b, bq1a, bq1b;      // phase-B chunks 0,1

  issueA(0, tc0, tc1, ti0, ti1);
  issueA(1, cc0, cc1, ci0, ci1);
  stageA(0, tc0, tc1, ti0, ti1);
  lds_barrier();

  for (int c = 0; c < 8; ++c) {
    if (c < 6)        issueA(c + 2, nc0, nc1, ni0, ni1);
    else if (c == 6)  issueB(0, bq0a, bq0b);    // phase-B prefetch starts here
    else              issueB(1, bq1a, bq1b);
    if (c < 7)        stageA((c + 1) & 1, cc0, cc1, ci0, ci1);
    else              stageB(0, bq0a, bq0b);    // simgT0 aliases bufA0; c=7 MFMA reads bufA1
    mfmaA(c & 1);
    lds_barrier();
    cc0 = nc0; cc1 = nc1; ci0 = ni0; ci1 = ni1;
  }

  // dump raw dots into ssc (aliases bufA1 — dead after c=7 MFMA + barrier)
  if (wave < 12) {
#pragma unroll
    for (int i2 = 0; i2 < 4; ++i2)
      ssc[(mt * 16 + kq * 4 + i2) * 66 + nt * 16 + fm] = acc[i2];
  }
  // norm reductions across 32-thread row groups
#pragma unroll
  for (int off = 16; off > 0; off >>= 1) {
    cn0 += __shfl_down(cn0, off, 32);
    cn1 += __shfl_down(cn1, off, 32);
    in0 += __shfl_down(in0, off, 32);
    in1 += __shfl_down(in1, off, 32);
  }
  if ((tid & 31) == 0) {
    snc[trow]      = sqrtf(cn0);
    snc[trow + 32] = sqrtf(cn1);
    sni[trow]      = sqrtf(in0);
    if (trow < 16) sni[trow + 32] = sqrtf(in1);
  }
  lds_barrier();

  // ---------------- softmax over r, per t (wave 0; lane = t) ----------------
  if (wave == 0) {
    float cn = snc[lane];
    float s[RREG];
    float mx = -1e30f;
#pragma unroll
    for (int r = 0; r < RREG; ++r) {
      float denom = fmaxf(sni[r] * cn, 1e-8f);
      float v = ssc[r * 66 + lane] / denom;
      s[r] = v;
      mx = fmaxf(mx, v);
    }
    float sum = 0.f;
#pragma unroll
    for (int r = 0; r < RREG; ++r) { float e = __expf(s[r] - mx); s[r] = e; sum += e; }
    float rinv = 1.f / sum;
    unsigned short* ap = satt + lane * 48;
#pragma unroll
    for (int r = 0; r < RREG; ++r) ap[r] = f2bf(s[r] * rinv);
#pragma unroll
    for (int r = RREG; r < 48; ++r) ap[r] = 0;
  }
  lds_barrier();

  // ---------------- Phase B: out = attn^T(64x36) . img(36x1024) ----------------
  const int mtB = wave >> 2;   // t-tile 0..3
  const unsigned short* arowB = satt + (mtB * 16 + fm) * 48;
  bf16x8 a1 = *(const bf16x8*)(arowB + kq * 8);            // k = 0..31
  bf16x8 a2 = {0, 0, 0, 0, 0, 0, 0, 0};                    // k = 32..47 (48..63 zero)
  if (kq < 2) a2 = *(const bf16x8*)(arowB + 32 + kq * 8);

  float4 pq0 = bq1a, pq1 = bq1b;   // chunk 1 data (loaded during phase A c=7)
  float4 nq0, nq1;

  for (int cb = 0; cb < 8; ++cb) {
    if (cb < 6) issueB(cb + 2, nq0, nq1);
    if (cb < 7) stageB((cb + 1) & 1, pq0, pq1);   // writes other buffer than MFMA reads
    {
      const unsigned short* st = (const unsigned short*)(smem + (cb & 1) * 14336);
#pragma unroll
      for (int j = 0; j < 2; ++j) {
        const int ntB = (wave & 3) * 2 + j;       // d-tile within chunk: 0..7
        const unsigned short* brow = st + (ntB * 16 + fm) * 56;
        bf16x8 b1 = *(const bf16x8*)(brow + kq * 8);
        bf16x8 b2 = {0, 0, 0, 0, 0, 0, 0, 0};
        if (kq < 2) b2 = *(const bf16x8*)(brow + 32 + kq * 8);
        f32x4 o = {0.f, 0.f, 0.f, 0.f};
        o = __builtin_amdgcn_mfma_f32_16x16x32_bf16(a1, b1, o, 0, 0, 0);
        o = __builtin_amdgcn_mfma_f32_16x16x32_bf16(a2, b2, o, 0, 0, 0);
#pragma unroll
        for (int i2 = 0; i2 < 4; ++i2)
          outb[(mtB * 16 + kq * 4 + i2) * DDIM + cb * 128 + ntB * 16 + fm] = o[i2];
      }
    }
    lds_barrier();
    pq0 = nq0; pq1 = nq1;
  }
}

extern "C" void kernel_launch(void* const* d_in, const int* in_sizes, int n_in,
                              void* d_out, int out_size, void* d_ws, size_t ws_size,
                              hipStream_t stream) {
  const float* img = (const float*)d_in[0];   // (256, 36, 1024) fp32
  const float* cap = (const float*)d_in[1];   // (256, 64, 1024) fp32
  // d_in[2] = cap_mask, unused by reference forward
  float* out = (float*)d_out;                 // (256, 64, 1024) fp32
  scan_fused<<<dim3(256), dim3(1024), 0, stream>>>(img, cap, out);
}